// Round 4
// baseline (853.276 us; speedup 1.0000x reference)
//
#include <hip/hip_runtime.h>
#include <hip/hip_bf16.h>

// Problem constants (from reference)
#define BATCH 16
#define SEQ_LEN 50
#define N_POINTS 25
#define SDF_H 100
#define SDF_W 100

typedef float vfloat4 __attribute__((ext_vector_type(4)));

// ---------------------------------------------------------------------------
// Zero-fill: each lane writes 64 B (4 x dwordx4) per loop trip; a wave covers
// 4 KiB contiguous. Plain (cached) stores — R3 showed NT stores ran at only
// ~1.4 TB/s effective; let L2 write-combine full lines instead.
// Buffer = 800 MB = 12.5M 64B-chunks. grid 4096 x 256 lanes -> ~12 trips/lane.
// ---------------------------------------------------------------------------
__global__ void zero_fill_kernel(vfloat4* __restrict__ out, size_t nchunks) {
    const vfloat4 z = {0.f, 0.f, 0.f, 0.f};
    size_t i = (size_t)blockIdx.x * blockDim.x + threadIdx.x;
    const size_t stride = (size_t)gridDim.x * blockDim.x;
    for (; i < nchunks; i += stride) {
        vfloat4* p = out + i * 4;
        p[0] = z;
        p[1] = z;
        p[2] = z;
        p[3] = z;
    }
}

// ---------------------------------------------------------------------------
// Scatter kernel: one thread per (b, t, p). Total B*T*P = 20000 threads.
// ---------------------------------------------------------------------------
__global__ void raster_scatter_kernel(const float* __restrict__ x,
                                      const float* __restrict__ resolution,
                                      const float* __restrict__ origin,
                                      float* __restrict__ out) {
    int gid = blockIdx.x * blockDim.x + threadIdx.x;
    const int total = BATCH * SEQ_LEN * N_POINTS;
    if (gid >= total) return;

    int p  = gid % N_POINTS;
    int bt = gid / N_POINTS;        // b*SEQ_LEN + t

    const float px = x[bt * (2 * N_POINTS) + 2 * p];
    const float py = x[bt * (2 * N_POINTS) + 2 * p + 1];

    const float r0 = resolution[bt * 2 + 0];
    const float r1 = resolution[bt * 2 + 1];
    const float o0 = origin[bt * 2 + 0];
    const float o1 = origin[bt * 2 + 1];

    // float32 divide + add, truncate toward zero (matches reference cast).
    int col = (int)(px / r0 + o0);
    int row = (int)(py / r1 + o1);

    // Mirror JAX scatter index clamping (defensive; inputs land in [25,75)).
    col = min(max(col, 0), SDF_W - 1);
    row = min(max(row, 0), SDF_H - 1);

    const size_t off =
        ((((size_t)bt * SDF_H + row) * SDF_W + col) * N_POINTS) + p;
    out[off] = 1.0f;
}

extern "C" void kernel_launch(void* const* d_in, const int* in_sizes, int n_in,
                              void* d_out, int out_size, void* d_ws, size_t ws_size,
                              hipStream_t stream) {
    const float* x          = (const float*)d_in[0];
    const float* resolution = (const float*)d_in[1];
    const float* origin     = (const float*)d_in[2];
    float* out = (float*)d_out;

    // 1) Zero the full output. out_size = 2e8 floats = 800 MB = 12.5M x 64B.
    const size_t nchunks = (size_t)out_size / 16;  // 16 floats (64 B) per chunk
    const int fill_block = 256;
    const int fill_grid = 4096;
    zero_fill_kernel<<<fill_grid, fill_block, 0, stream>>>((vfloat4*)out, nchunks);

    // 2) Scatter the 20000 ones (stream-ordered after the fill).
    const int total = BATCH * SEQ_LEN * N_POINTS;
    const int block = 256;
    const int grid = (total + block - 1) / block;
    raster_scatter_kernel<<<grid, block, 0, stream>>>(x, resolution, origin, out);
}

// Round 5
// 757.641 us; speedup vs baseline: 1.1262x; 1.1262x over previous
//
#include <hip/hip_runtime.h>
#include <hip/hip_bf16.h>

// Problem constants (from reference)
#define BATCH 16
#define SEQ_LEN 50
#define N_POINTS 25
#define SDF_H 100
#define SDF_W 100

// ---------------------------------------------------------------------------
// R4 post-mortem: dur_us includes ~635 us of harness poison fills (the 3.2 GB
// WRITE_SIZE fillBufferAligned rows are the 0xAA poison of d_ws, at 6.2 TB/s).
// Our controllable part is zero(800 MB) + scatter(20000 ones). The graph
// memset node runs at ~6.3 TB/s (= write roofline, ~127 us); our hand-rolled
// fills measured slower (NT ~4.3 TB/s, cached ~3.7 TB/s). So: memset + tiny
// scatter is optimal. This reverts to the R1 configuration.
// ---------------------------------------------------------------------------

// Scatter kernel: one thread per (b, t, p). Total B*T*P = 20000 threads.
__global__ void raster_scatter_kernel(const float* __restrict__ x,
                                      const float* __restrict__ resolution,
                                      const float* __restrict__ origin,
                                      float* __restrict__ out) {
    int gid = blockIdx.x * blockDim.x + threadIdx.x;
    const int total = BATCH * SEQ_LEN * N_POINTS;
    if (gid >= total) return;

    int p  = gid % N_POINTS;
    int bt = gid / N_POINTS;        // b*SEQ_LEN + t

    const float px = x[bt * (2 * N_POINTS) + 2 * p];
    const float py = x[bt * (2 * N_POINTS) + 2 * p + 1];

    const float r0 = resolution[bt * 2 + 0];
    const float r1 = resolution[bt * 2 + 1];
    const float o0 = origin[bt * 2 + 0];
    const float o1 = origin[bt * 2 + 1];

    // float32 divide + add, truncate toward zero (matches reference cast).
    int col = (int)(px / r0 + o0);
    int row = (int)(py / r1 + o1);

    // Mirror JAX scatter index clamping (defensive; inputs land in [25,75)).
    col = min(max(col, 0), SDF_W - 1);
    row = min(max(row, 0), SDF_H - 1);

    const size_t off =
        ((((size_t)bt * SDF_H + row) * SDF_W + col) * N_POINTS) + p;
    out[off] = 1.0f;
}

extern "C" void kernel_launch(void* const* d_in, const int* in_sizes, int n_in,
                              void* d_out, int out_size, void* d_ws, size_t ws_size,
                              hipStream_t stream) {
    const float* x          = (const float*)d_in[0];
    const float* resolution = (const float*)d_in[1];
    const float* origin     = (const float*)d_in[2];
    float* out = (float*)d_out;

    // 1) Zero the full output. The graph-captured memset node runs at the
    //    ~6.3 TB/s write ceiling — faster than any hand-rolled fill we tried.
    hipMemsetAsync(out, 0, (size_t)out_size * sizeof(float), stream);

    // 2) Scatter the 20000 ones (stream-ordered after the fill).
    const int total = BATCH * SEQ_LEN * N_POINTS;
    const int block = 256;
    const int grid = (total + block - 1) / block;
    raster_scatter_kernel<<<grid, block, 0, stream>>>(x, resolution, origin, out);
}